// Round 8
// baseline (628.176 us; speedup 1.0000x reference)
//
#include <hip/hip_runtime.h>
#include <cstdint>
#include <cstddef>

using f16   = _Float16;
using f16x4 = __attribute__((ext_vector_type(4))) _Float16;
using f16x8 = __attribute__((ext_vector_type(8))) _Float16;
using f32x4 = __attribute__((ext_vector_type(4))) float;

__device__ __forceinline__ f32x4 mfma16(f16x8 a, f16x8 b, f32x4 c) {
  return __builtin_amdgcn_mfma_f32_16x16x32_f16(a, b, c, 0, 0, 0);
}

__device__ __forceinline__ void gld16(const f16* g, f16* l) {
  __builtin_amdgcn_global_load_lds(
      (__attribute__((address_space(1))) void*)g,
      (__attribute__((address_space(3))) void*)l, 16, 0, 0);
}

constexpr int BATCH = 2, SEQL = 2048, HID = 1024, NH = 16, DH = 64;
constexpr int TOK = BATCH * SEQL;   // 4096
constexpr int NQKV = 3 * HID;       // 3072
constexpr int NBLK = 512;

// Sense-reversal grid barrier. All NBLK blocks must be co-resident:
// guaranteed by launch_bounds(256,2) + LDS 36.8KB (per-CU capacity >= 2,
// 256 CUs -> >= 512 slots). cnt/gen zeroed by hipMemsetAsync before launch.
// Release: each block __threadfence()s its writes before arriving (RMW chain
// on cnt gives transitivity); last arriver resets cnt, fences, bumps gen.
__device__ __forceinline__ void grid_barrier(volatile unsigned* cnt,
                                             volatile unsigned* gen) {
  __threadfence();
  __syncthreads();
  if (threadIdx.x == 0) {
    unsigned g = *gen;
    if (atomicAdd((unsigned*)cnt, 1u) == NBLK - 1) {
      *cnt = 0;
      __threadfence();
      *gen = g + 1;
    } else {
      while (*gen == g) __builtin_amdgcn_s_sleep(2);
    }
  }
  __syncthreads();
  __threadfence();
}

// One persistent kernel: prep -> QKV GEMM -> attention -> out GEMM, separated
// by the manual grid barrier. 512 blocks x 256 threads.
__global__ __launch_bounds__(256, 2) void k_mega(
    const float* __restrict__ x,
    const float* __restrict__ Wq, const float* __restrict__ bq,
    const float* __restrict__ Wk, const float* __restrict__ bk,
    const float* __restrict__ Wv, const float* __restrict__ bv,
    const float* __restrict__ Wo, const float* __restrict__ bo,
    f16* __restrict__ xh, f16* __restrict__ WT, f16* __restrict__ WoT,
    f16* __restrict__ Qh, f16* __restrict__ Kh, f16* __restrict__ Vp,
    f16* __restrict__ Ao, float* __restrict__ out, unsigned* bar) {
  __shared__ union SM {
    float wt[32][33];                                    // prep transpose
    struct { f16 A[128 * 32]; f16 B[128 * 32]; } g;      // qkv gemm (16KB)
    struct { f16 K[2][64 * 72]; f16 V[2][64 * 72]; } at; // attn (36.8KB)
    struct { f16 A[128 * 32]; f16 B[64 * 32]; } og;      // out gemm (12KB)
  } sm;
  const int bid = blockIdx.x, tid = threadIdx.x;
  const int lane = tid & 63, w = tid >> 6, lr = lane & 15, lq = lane >> 4;
  volatile unsigned* cnt = bar;       // d_out[0]; overwritten by phase 4
  volatile unsigned* gen = bar + 1;   // d_out[1]

  // ================= phase 1: prep =================
  {
    int base = bid * 8192 + tid * 4;
#pragma unroll
    for (int j = 0; j < 8; j++) {
      int i = base + j * 1024;
      float4 v = *(const float4*)(x + i);
      f16x4 o = { (f16)v.x, (f16)v.y, (f16)v.z, (f16)v.w };
      *(f16x4*)(xh + i) = o;
    }
    int c = tid & 31, r8 = tid >> 5;
    for (int it = 0; it < 8; it++) {
      int t = bid * 8 + it;
      int mat = t >> 10, rem = t & 1023;
      const float* W = (mat == 0) ? Wq : (mat == 1) ? Wk : (mat == 2) ? Wv : Wo;
      int in0 = (rem & 31) * 32, out0 = (rem >> 5) * 32;
      __syncthreads();
#pragma unroll
      for (int i = 0; i < 4; i++) {
        int r = r8 + i * 8;
        sm.wt[r][c] = W[(size_t)(in0 + r) * HID + out0 + c];
      }
      __syncthreads();
#pragma unroll
      for (int i = 0; i < 4; i++) {
        int r = r8 + i * 8;
        f16 v = (f16)sm.wt[c][r];
        if (mat == 3) WoT[(size_t)(out0 + r) * HID + in0 + c] = v;
        else          WT[(size_t)(mat * HID + out0 + r) * HID + in0 + c] = v;
      }
    }
  }
  grid_barrier(cnt, gen);

  // ===== phase 2: QKV GEMM, 768 tiles static split (blocks 0..255 get 2) ====
  {
    constexpr int K = HID;
    int wm = w >> 1, wn = w & 1;
    int row0 = tid >> 2, seg0 = tid & 3, row1 = row0 + 64;
    for (int t = bid; t < 768; t += NBLK) {
      int m0 = (t & 31) * 128, n0 = (t >> 5) * 128;
      const f16* Ag0 = xh + (size_t)(m0 + row0) * K + seg0 * 8;
      const f16* Ag1 = xh + (size_t)(m0 + row1) * K + seg0 * 8;
      const f16* Bg0 = WT + (size_t)(n0 + row0) * K + seg0 * 8;
      const f16* Bg1 = WT + (size_t)(n0 + row1) * K + seg0 * 8;
      f32x4 acc[4][4];
#pragma unroll
      for (int i = 0; i < 4; i++)
#pragma unroll
        for (int j = 0; j < 4; j++) acc[i][j] = (f32x4){0.f, 0.f, 0.f, 0.f};

      for (int k0 = 0; k0 < K; k0 += 32) {
        __syncthreads();
        gld16(Ag0 + k0, sm.g.A + tid * 8);
        gld16(Ag1 + k0, sm.g.A + (256 + tid) * 8);
        gld16(Bg0 + k0, sm.g.B + tid * 8);
        gld16(Bg1 + k0, sm.g.B + (256 + tid) * 8);
        __syncthreads();
        f16x8 af[4], bfr[4];
#pragma unroll
        for (int mt = 0; mt < 4; mt++)
          af[mt] = *(const f16x8*)(sm.g.A + (wm * 64 + mt * 16 + lr) * 32 + lq * 8);
#pragma unroll
        for (int nt = 0; nt < 4; nt++)
          bfr[nt] = *(const f16x8*)(sm.g.B + (wn * 64 + nt * 16 + lr) * 32 + lq * 8);
#pragma unroll
        for (int mt = 0; mt < 4; mt++)
#pragma unroll
          for (int nt = 0; nt < 4; nt++)
            acc[mt][nt] = mfma16(af[mt], bfr[nt], acc[mt][nt]);
      }

#pragma unroll
      for (int nt = 0; nt < 4; nt++) {
        int o = n0 + wn * 64 + nt * 16 + lr;
        int sec = o >> 10, o1 = o & 1023, hh = o1 >> 6, dd = o1 & 63;
        float bias = (sec == 0) ? bq[o1] : (sec == 1) ? bk[o1] : bv[o1];
#pragma unroll
        for (int mt = 0; mt < 4; mt++) {
          int t0 = m0 + wm * 64 + mt * 16 + lq * 4;
          int b = t0 >> 11, s0 = t0 & (SEQL - 1);
          size_t bh = (size_t)(b * NH + hh);
          if (sec == 2) {
            f16x4 pv = { (f16)(acc[mt][nt][0] + bias), (f16)(acc[mt][nt][1] + bias),
                         (f16)(acc[mt][nt][2] + bias), (f16)(acc[mt][nt][3] + bias) };
            int pb = (s0 & ~31) | ((s0 & 12) << 1) | ((s0 >> 2) & 4);
            *(f16x4*)(Vp + (bh * DH + dd) * SEQL + pb) = pv;  // V^T permuted keys
          } else {
            f16* dst = (sec == 0) ? Qh : Kh;
#pragma unroll
            for (int r = 0; r < 4; r++)
              dst[(bh * SEQL + s0 + r) * DH + dd] = (f16)(acc[mt][nt][r] + bias);
          }
        }
      }
    }
  }
  grid_barrier(cnt, gen);

  // ================= phase 3: attention =================
  {
    int bh = bid & 31;          // bid%8 = bh%8 -> XCD-local K/V in L2
    int qblk = bid >> 5;
    int b = bh >> 4, h = bh & 15;

    f16x8 qf[2][2];
#pragma unroll
    for (int qt = 0; qt < 2; qt++) {
      const f16* Qbase =
          Qh + ((size_t)bh * SEQL + qblk * 128 + w * 32 + qt * 16 + lr) * DH;
#pragma unroll
      for (int ks = 0; ks < 2; ks++) {
        qf[qt][ks] = *(const f16x8*)(Qbase + ks * 32 + lq * 8);
        qf[qt][ks] = qf[qt][ks] * (f16)0.18033688f;   // 1/8 * log2(e)
      }
    }

    f32x4 O[2][4];
#pragma unroll
    for (int qt = 0; qt < 2; qt++)
#pragma unroll
      for (int dt = 0; dt < 4; dt++) O[qt][dt] = (f32x4){0.f, 0.f, 0.f, 0.f};
    float lsum[2] = {0.f, 0.f};

    int srow = tid >> 3, sseg = tid & 7, srow1 = srow + 32;
    const f16* Kg0 = Kh + ((size_t)bh * SEQL + srow) * DH + sseg * 8;
    const f16* Kg1 = Kh + ((size_t)bh * SEQL + srow1) * DH + sseg * 8;
    const f16* Vg0 = Vp + ((size_t)bh * DH + srow) * SEQL + sseg * 8;
    const f16* Vg1 = Vp + ((size_t)bh * DH + srow1) * SEQL + sseg * 8;

    uint4 kr0 = *(const uint4*)(Kg0), kr1 = *(const uint4*)(Kg1);
    uint4 vr0 = *(const uint4*)(Vg0), vr1 = *(const uint4*)(Vg1);

    for (int kb = 0; kb < SEQL / 64; kb++) {
      f16* Kp = sm.at.K[kb & 1];
      f16* Vq = sm.at.V[kb & 1];
      *(uint4*)(Kp + srow * 72 + sseg * 8) = kr0;
      *(uint4*)(Kp + srow1 * 72 + sseg * 8) = kr1;
      *(uint4*)(Vq + srow * 72 + sseg * 8) = vr0;
      *(uint4*)(Vq + srow1 * 72 + sseg * 8) = vr1;
      if (kb < SEQL / 64 - 1) {
        size_t ko = (size_t)(kb + 1) * 64 * DH;
        int vo = (kb + 1) * 64;
        kr0 = *(const uint4*)(Kg0 + ko);
        kr1 = *(const uint4*)(Kg1 + ko);
        vr0 = *(const uint4*)(Vg0 + vo);
        vr1 = *(const uint4*)(Vg1 + vo);
      }
      __syncthreads();

      f32x4 sacc[2][4];
#pragma unroll
      for (int qt = 0; qt < 2; qt++)
#pragma unroll
        for (int kt = 0; kt < 4; kt++) sacc[qt][kt] = (f32x4){0.f, 0.f, 0.f, 0.f};
#pragma unroll
      for (int ks = 0; ks < 2; ks++) {
#pragma unroll
        for (int kt = 0; kt < 4; kt++) {
          f16x8 kf = *(const f16x8*)(Kp + (kt * 16 + lr) * 72 + ks * 32 + lq * 8);
          sacc[0][kt] = mfma16(kf, qf[0][ks], sacc[0][kt]);
          sacc[1][kt] = mfma16(kf, qf[1][ks], sacc[1][kt]);
        }
      }

      f16x8 pf[2][2];
#pragma unroll
      for (int qt = 0; qt < 2; qt++) {
        float part = 0.f;
#pragma unroll
        for (int kt = 0; kt < 4; kt++) {
          float p0 = __builtin_amdgcn_exp2f(sacc[qt][kt][0]);
          float p1 = __builtin_amdgcn_exp2f(sacc[qt][kt][1]);
          float p2 = __builtin_amdgcn_exp2f(sacc[qt][kt][2]);
          float p3 = __builtin_amdgcn_exp2f(sacc[qt][kt][3]);
          part += (p0 + p1) + (p2 + p3);
          int s = kt >> 1, off = (kt & 1) * 4;
          pf[qt][s][off + 0] = (f16)p0; pf[qt][s][off + 1] = (f16)p1;
          pf[qt][s][off + 2] = (f16)p2; pf[qt][s][off + 3] = (f16)p3;
        }
        lsum[qt] += part;
      }

#pragma unroll
      for (int s = 0; s < 2; s++) {
#pragma unroll
        for (int dt = 0; dt < 4; dt++) {
          f16x8 vf = *(const f16x8*)(Vq + (dt * 16 + lr) * 72 + s * 32 + lq * 8);
          O[0][dt] = mfma16(vf, pf[0][s], O[0][dt]);
          O[1][dt] = mfma16(vf, pf[1][s], O[1][dt]);
        }
      }
    }

#pragma unroll
    for (int qt = 0; qt < 2; qt++) {
      float l1 = lsum[qt] + __shfl_xor(lsum[qt], 16);
      float ltot = l1 + __shfl_xor(l1, 32);
      float inv = 1.0f / ltot;
      int q = qblk * 128 + w * 32 + qt * 16 + lr;
      f16* dst = Ao + ((size_t)b * SEQL + q) * HID + h * DH;
#pragma unroll
      for (int dt = 0; dt < 4; dt++) {
        f16x4 o = { (f16)(O[qt][dt][0] * inv), (f16)(O[qt][dt][1] * inv),
                    (f16)(O[qt][dt][2] * inv), (f16)(O[qt][dt][3] * inv) };
        *(f16x4*)(dst + dt * 16 + lq * 4) = o;
      }
    }
  }
  grid_barrier(cnt, gen);

  // ================= phase 4: out GEMM (512 tiles of 128x64) =================
  {
    constexpr int K = HID;
    int m0 = (bid & 31) * 128, n0 = (bid >> 5) * 64;
    int wm = w >> 1, wn = w & 1;
    int row0 = tid >> 2, seg0 = tid & 3, row1 = row0 + 64;
    const f16* Ag0 = Ao + (size_t)(m0 + row0) * K + seg0 * 8;
    const f16* Ag1 = Ao + (size_t)(m0 + row1) * K + seg0 * 8;
    const f16* Bg0 = WoT + (size_t)(n0 + row0) * K + seg0 * 8;
    f32x4 acc[4][2];
#pragma unroll
    for (int i = 0; i < 4; i++)
#pragma unroll
      for (int j = 0; j < 2; j++) acc[i][j] = (f32x4){0.f, 0.f, 0.f, 0.f};

    for (int k0 = 0; k0 < K; k0 += 32) {
      __syncthreads();
      gld16(Ag0 + k0, sm.og.A + tid * 8);
      gld16(Ag1 + k0, sm.og.A + (256 + tid) * 8);
      gld16(Bg0 + k0, sm.og.B + tid * 8);
      __syncthreads();
      f16x8 af[4], bfr[2];
#pragma unroll
      for (int mt = 0; mt < 4; mt++)
        af[mt] = *(const f16x8*)(sm.og.A + (wm * 64 + mt * 16 + lr) * 32 + lq * 8);
#pragma unroll
      for (int nt = 0; nt < 2; nt++)
        bfr[nt] = *(const f16x8*)(sm.og.B + (wn * 32 + nt * 16 + lr) * 32 + lq * 8);
#pragma unroll
      for (int mt = 0; mt < 4; mt++)
#pragma unroll
        for (int nt = 0; nt < 2; nt++)
          acc[mt][nt] = mfma16(af[mt], bfr[nt], acc[mt][nt]);
    }

#pragma unroll
    for (int nt = 0; nt < 2; nt++) {
      int o = n0 + wn * 32 + nt * 16 + lr;
      float bias = bo[o];
#pragma unroll
      for (int mt = 0; mt < 4; mt++) {
        int t0 = m0 + wm * 64 + mt * 16 + lq * 4;
#pragma unroll
        for (int r = 0; r < 4; r++)
          out[(size_t)(t0 + r) * HID + o] = acc[mt][nt][r] + bias;
      }
    }
  }
}

// ---------------------------------------------------------------- launch
extern "C" void kernel_launch(void* const* d_in, const int* in_sizes, int n_in,
                              void* d_out, int out_size, void* d_ws, size_t ws_size,
                              hipStream_t stream) {
  const float* x  = (const float*)d_in[0];
  const float* Wq = (const float*)d_in[1];
  const float* bq = (const float*)d_in[2];
  const float* Wk = (const float*)d_in[3];
  const float* bk = (const float*)d_in[4];
  const float* Wv = (const float*)d_in[5];
  const float* bv = (const float*)d_in[6];
  const float* Wo = (const float*)d_in[7];
  const float* bo = (const float*)d_in[8];

  char* ws = (char*)d_ws;
  f16* xh  = (f16*)(ws + 0);                       //  8 MiB
  f16* WT  = (f16*)(ws + 8388608);                 //  6 MiB
  f16* WoT = (f16*)(ws + 14680064);                //  2 MiB
  f16* Qh  = (f16*)(ws + 16777216);                //  8 MiB [bh][s][d]
  f16* Kh  = (f16*)(ws + 25165824);                //  8 MiB [bh][s][d]
  f16* Vp  = (f16*)(ws + 33554432);                //  8 MiB [bh][d][key']
  f16* Ao  = (f16*)(ws + 41943040);                //  8 MiB [b][s][h*dv]
  float*    out = (float*)d_out;
  unsigned* bar = (unsigned*)d_out;   // barrier state; overwritten by phase 4

  hipMemsetAsync(d_out, 0, 16, stream);   // zero cnt/gen (graph-legal)
  k_mega<<<NBLK, 256, 0, stream>>>(x, Wq, bq, Wk, bk, Wv, bv, Wo, bo,
                                   xh, WT, WoT, Qh, Kh, Vp, Ao, out, bar);
}